// Round 3
// baseline (227.868 us; speedup 1.0000x reference)
//
#include <hip/hip_runtime.h>

// 8-level sym8 wavelet packet transform, B=128 rows of L0=65536, f32.
// LDS-staged: coalesced global->LDS fill, windowed reads from LDS with
// pad-swizzle phi(i)=i+(i>>4) to avoid bank conflicts.
// Level lengths: 65536->32775->16395->8205->4110->2062->1038->526->270.
// Levels 0-2: segment-per-block kernel (1024 outputs, NO=4/thread).
// Levels 3-7: whole rows in LDS, R rows/block, NO outputs/thread.
// Final level fuses log(x^2 + 1e-12).

#define PHI(i) ((i) + ((i) >> 4))

// fl[t] = dec_lo[15-t]  (flipped low-pass, cross-correlation form)
__device__ __constant__ float FL[16] = {
     0.0018899503327594609f, -0.0003029205147213668f, -0.01495225833704823f,
     0.003808752013890615f,   0.049137179673607506f,  -0.027219029917056003f,
    -0.05194583810770904f,    0.3644418948353314f,     0.7771857517005235f,
     0.4813596512583722f,    -0.061273359067658524f,  -0.1432942383508097f,
     0.007607487324917605f,   0.03169508781149298f,   -0.0005421323317911481f,
    -0.0033824159510061256f
};

// fh[t] = dec_hi[15-t] = (t odd ? +1 : -1) * dec_lo[t]
__device__ __constant__ float FH[16] = {
     0.0033824159510061256f, -0.0005421323317911481f, -0.03169508781149298f,
     0.007607487324917605f,   0.1432942383508097f,    -0.061273359067658524f,
    -0.4813596512583722f,     0.7771857517005235f,    -0.3644418948353314f,
    -0.05194583810770904f,    0.027219029917056003f,   0.049137179673607506f,
    -0.003808752013890615f,  -0.01495225833704823f,    0.0003029205147213668f,
     0.0018899503327594609f
};

// ---------- Kernel A: levels 0-2, one 1024-output segment per block ----------
// 256 threads x NO=4 consecutive outputs. Input window 2*1024+14 = 2062 floats.
__global__ __launch_bounds__(256) void dwt_seg(
    const float* __restrict__ x, float* __restrict__ y, int Lin, int Lout) {
    __shared__ float lds[PHI(2062) + 2];
    const int seg = blockIdx.x;
    const int n = blockIdx.y;
    const float* row = x + (size_t)n * (size_t)Lin;
    const int base = 2 * (seg * 1024) - 14;
    const int W = 2062;

    const bool edge = (base < 0) || (base + W > Lin);
    if (edge) {
        for (int p = threadIdx.x; p < W; p += 256) {
            int q = base + p;
            q = (q < 0) ? -q : q;
            q = (q >= Lin) ? (2 * Lin - 2 - q) : q;
            lds[PHI(p)] = row[q];
        }
    } else {
        for (int p = threadIdx.x; p < W; p += 256) {
            lds[PHI(p)] = row[base + p];
        }
    }
    __syncthreads();

    const int tid = threadIdx.x;
    float w[22];
#pragma unroll
    for (int t = 0; t < 22; ++t) w[t] = lds[PHI(8 * tid + t)];

    float lo[4], hi[4];
#pragma unroll
    for (int i = 0; i < 4; ++i) { lo[i] = 0.0f; hi[i] = 0.0f; }
#pragma unroll
    for (int t = 0; t < 16; ++t) {
        const float cl = FL[t];
        const float ch = FH[t];
#pragma unroll
        for (int i = 0; i < 4; ++i) {
            const float v = w[2 * i + t];
            lo[i] = fmaf(v, cl, lo[i]);
            hi[i] = fmaf(v, ch, hi[i]);
        }
    }

    const int j0 = seg * 1024 + tid * 4;
    float* y0 = y + (size_t)(2 * n) * (size_t)Lout + (size_t)j0;
    float* y1 = y0 + Lout;
#pragma unroll
    for (int i = 0; i < 4; ++i) {
        if (j0 + i < Lout) { y0[i] = lo[i]; y1[i] = hi[i]; }
    }
}

// ---------- Kernel B: levels 3-7, R whole rows per block ----------
template <int NO, int R, int LINMAX, bool FUSE_LOG>
__global__ __launch_bounds__(256) void dwt_rows(
    const float* __restrict__ x, float* __restrict__ y,
    int Lin, int Lout, int gpr) {
    __shared__ float lds[PHI(R * LINMAX) + 2];
    const int n0 = blockIdx.x * R;
    const float* src = x + (size_t)n0 * (size_t)Lin;
    const int T = R * Lin;
    for (int p = threadIdx.x; p < T; p += 256) lds[PHI(p)] = src[p];
    __syncthreads();

    const int tid = threadIdx.x;
    const int r = tid / gpr;
    if (r >= R) return;
    const int g = tid - r * gpr;
    const int j0 = g * NO;
    const int aBase = r * Lin;
    const int p0 = 2 * j0 - 14;

    float w[2 * NO + 14];
#pragma unroll
    for (int t = 0; t < 2 * NO + 14; ++t) {
        int q = p0 + t;
        q = (q < 0) ? -q : q;
        q = (q >= Lin) ? (2 * Lin - 2 - q) : q;
        w[t] = lds[PHI(aBase + q)];
    }

    float lo[NO], hi[NO];
#pragma unroll
    for (int i = 0; i < NO; ++i) { lo[i] = 0.0f; hi[i] = 0.0f; }
#pragma unroll
    for (int t = 0; t < 16; ++t) {
        const float cl = FL[t];
        const float ch = FH[t];
#pragma unroll
        for (int i = 0; i < NO; ++i) {
            const float v = w[2 * i + t];
            lo[i] = fmaf(v, cl, lo[i]);
            hi[i] = fmaf(v, ch, hi[i]);
        }
    }

    const int n = n0 + r;
    float* y0 = y + (size_t)(2 * n) * (size_t)Lout + (size_t)j0;
    float* y1 = y0 + Lout;
#pragma unroll
    for (int i = 0; i < NO; ++i) {
        if (j0 + i < Lout) {
            if (FUSE_LOG) {
                y0[i] = logf(fmaf(lo[i], lo[i], 1e-12f));
                y1[i] = logf(fmaf(hi[i], hi[i], 1e-12f));
            } else {
                y0[i] = lo[i];
                y1[i] = hi[i];
            }
        }
    }
}

extern "C" void kernel_launch(void* const* d_in, const int* in_sizes, int n_in,
                              void* d_out, int out_size, void* d_ws, size_t ws_size,
                              hipStream_t stream) {
    const float* in = (const float*)d_in[0];
    float* ws  = (float*)d_ws;   // even-level outputs (max ~34.5 MB)
    float* out = (float*)d_out;  // odd-level scratch + final output

    // Level lengths: 65536->32775->16395->8205->4110->2062->1038->526->270
    // lev0: A  65536->32775, N=128,  segs=33, dst=ws
    { dim3 g(33, 128);  dwt_seg<<<g, 256, 0, stream>>>(in, ws, 65536, 32775); }
    // lev1: A  32775->16395, N=256,  segs=17, dst=out
    { dim3 g(17, 256);  dwt_seg<<<g, 256, 0, stream>>>(ws, out, 32775, 16395); }
    // lev2: A  16395->8205,  N=512,  segs=9,  dst=ws
    { dim3 g(9, 512);   dwt_seg<<<g, 256, 0, stream>>>(out, ws, 16395, 8205); }
    // lev3: B<17,1>  8205->4110,  N=1024,  gpr=ceil(4110/17)=242, dst=out
    dwt_rows<17, 1, 8205, false><<<1024, 256, 0, stream>>>(ws, out, 8205, 4110, 242);
    // lev4: B<9,1>   4110->2062,  N=2048,  gpr=ceil(2062/9)=230,  dst=ws
    dwt_rows<9, 1, 4110, false><<<2048, 256, 0, stream>>>(out, ws, 4110, 2062, 230);
    // lev5: B<5,1>   2062->1038,  N=4096,  gpr=ceil(1038/5)=208,  dst=out
    dwt_rows<5, 1, 2062, false><<<4096, 256, 0, stream>>>(ws, out, 2062, 1038, 208);
    // lev6: B<5,2>   1038->526,   N=8192,  gpr=ceil(526/5)=106,   dst=ws
    dwt_rows<5, 2, 1038, false><<<4096, 256, 0, stream>>>(out, ws, 1038, 526, 106);
    // lev7: B<5,4>   526->270,    N=16384, gpr=270/5=54, dst=out, fuse log
    dwt_rows<5, 4, 526, true><<<4096, 256, 0, stream>>>(ws, out, 526, 270, 54);
}

// Round 4
// 107.702 us; speedup vs baseline: 2.1157x; 2.1157x over previous
//
#include <hip/hip_runtime.h>

// 8-level sym8 wavelet packet transform, B=128 rows of L0=65536, f32.
// Fused into 3 kernels: F01 (levels 0-1), F23 (levels 2-3), F47 (levels 4-7).
// Level lengths: 65536->32775->16395->8205->4110->2062->1038->526->270.
// All intermediate subband tiles live in LDS (PHI pad-swizzle, ~2-way max);
// only levels 1, 3, and the final log-power output touch global memory.

#define PHI(i) ((i) + ((i) >> 4))

// fl[t] = dec_lo[15-t]  (flipped low-pass, cross-correlation form)
__device__ __constant__ float FL[16] = {
     0.0018899503327594609f, -0.0003029205147213668f, -0.01495225833704823f,
     0.003808752013890615f,   0.049137179673607506f,  -0.027219029917056003f,
    -0.05194583810770904f,    0.3644418948353314f,     0.7771857517005235f,
     0.4813596512583722f,    -0.061273359067658524f,  -0.1432942383508097f,
     0.007607487324917605f,   0.03169508781149298f,   -0.0005421323317911481f,
    -0.0033824159510061256f
};

// fh[t] = dec_hi[15-t] = (t odd ? +1 : -1) * dec_lo[t]
__device__ __constant__ float FH[16] = {
     0.0033824159510061256f, -0.0005421323317911481f, -0.03169508781149298f,
     0.007607487324917605f,   0.1432942383508097f,    -0.061273359067658524f,
    -0.4813596512583722f,     0.7771857517005235f,    -0.3644418948353314f,
    -0.05194583810770904f,    0.027219029917056003f,   0.049137179673607506f,
    -0.003808752013890615f,  -0.01495225833704823f,    0.0003029205147213668f,
     0.0018899503327594609f
};

// ---------------- Fused two-level kernel (levels k, k+1) ----------------
// Input: rows of length LIN. Level-A length LA = ceil(LIN/2)+7,
// level-B length LB = ceil(LA/2)+7. Block = (row n, segment of MB=512
// level-B outputs). A-tile (both lo/hi subrows) of WA=1038 genuine
// positions [a_lo, a_lo+WA) lives in LDS; B reads reflect-then-lookup.
template <int LIN, int LA, int LB>
__global__ __launch_bounds__(256) void dwt_pair(
    const float* __restrict__ x, float* __restrict__ y) {
    constexpr int MB = 512;
    constexpr int WA = 2 * MB + 14;   // 1038 (even)
    constexpr int WX = 2 * WA + 14;   // 2090
    __shared__ float xs[PHI(WX) + 2];
    __shared__ float as[PHI(2 * WA) + 2];

    const int seg = blockIdx.x;
    const int n   = blockIdx.y;
    const int b0  = seg * MB;

    int a_lo = 2 * b0 - 14;
    if (a_lo < 0) a_lo = 0;
    if (a_lo > LA - WA) a_lo = LA - WA;
    const int px0 = 2 * a_lo - 14;

    const float* row = x + (size_t)n * (size_t)LIN;

    // x-tile fill (coalesced; reflect folded into the fill)
    for (int p = threadIdx.x; p < WX; p += 256) {
        int q = px0 + p;
        q = (q < 0) ? -q : q;
        q = (q >= LIN) ? (2 * LIN - 2 - q) : q;
        xs[PHI(p)] = row[q];
    }
    __syncthreads();

    // A-phase: genuine positions s in [0, WA), two at a time, both filters
    for (int g = threadIdx.x; g < WA / 2; g += 256) {
        const int s0 = 2 * g;
        float w[18];
#pragma unroll
        for (int t = 0; t < 18; ++t) w[t] = xs[PHI(2 * s0 + t)];
        float lo0 = 0.f, hi0 = 0.f, lo1 = 0.f, hi1 = 0.f;
#pragma unroll
        for (int t = 0; t < 16; ++t) {
            const float cl = FL[t], ch = FH[t];
            lo0 = fmaf(w[t],     cl, lo0);
            hi0 = fmaf(w[t],     ch, hi0);
            lo1 = fmaf(w[t + 2], cl, lo1);
            hi1 = fmaf(w[t + 2], ch, hi1);
        }
        as[PHI(s0)]          = lo0;
        as[PHI(s0 + 1)]      = lo1;
        as[PHI(WA + s0)]     = hi0;
        as[PHI(WA + s0 + 1)] = hi1;
    }
    __syncthreads();

    // B-phase: one group per thread: sA = tid>>7, 4 consecutive j
    const int sA = threadIdx.x >> 7;
    const int j0 = b0 + (threadIdx.x & 127) * 4;
    if (j0 >= LB) return;

    const int q0 = 2 * j0 - 14;
    const int aBase = sA * WA - a_lo;
    float w[22];
    if (q0 >= a_lo && q0 + 22 <= a_lo + WA) {
#pragma unroll
        for (int t = 0; t < 22; ++t) w[t] = as[PHI(aBase + q0 + t)];
    } else {
#pragma unroll
        for (int t = 0; t < 22; ++t) {
            int q = q0 + t;
            q = (q < 0) ? -q : q;
            q = (q >= LA) ? (2 * LA - 2 - q) : q;
            w[t] = as[PHI(aBase + q)];
        }
    }

    float lo[4], hi[4];
#pragma unroll
    for (int i = 0; i < 4; ++i) { lo[i] = 0.f; hi[i] = 0.f; }
#pragma unroll
    for (int t = 0; t < 16; ++t) {
        const float cl = FL[t], ch = FH[t];
#pragma unroll
        for (int i = 0; i < 4; ++i) {
            const float v = w[2 * i + t];
            lo[i] = fmaf(v, cl, lo[i]);
            hi[i] = fmaf(v, ch, hi[i]);
        }
    }

    float* y0 = y + (size_t)(4 * n + 2 * sA) * (size_t)LB + (size_t)j0;
    float* y1 = y0 + LB;
#pragma unroll
    for (int i = 0; i < 4; ++i) {
        if (j0 + i < LB) { y0[i] = lo[i]; y1[i] = hi[i]; }
    }
}

// ---------------- Fused four-level kernel (levels 4-7) ----------------
// One lev-3 subrow (4110 floats) per block; whole subtree in LDS.
template <int LIN, int P, bool LOG>
__device__ __forceinline__ void f47_stage(const float* __restrict__ in,
                                          float* __restrict__ outl,
                                          float* __restrict__ outg) {
    constexpr int LOUT = LIN / 2 + 7;
    constexpr int GPC = (LOUT + 3) / 4;
    constexpr int G = P * GPC;
    for (int g = threadIdx.x; g < G; g += 256) {
        const int p  = g / GPC;            // compile-time divisor
        const int jg = g - p * GPC;
        const int j0 = jg * 4;
        const int q0 = 2 * j0 - 14;
        const int ib = p * LIN;

        float w[22];
        if (q0 >= 0 && q0 + 22 <= LIN) {
#pragma unroll
            for (int t = 0; t < 22; ++t) w[t] = in[PHI(ib + q0 + t)];
        } else {
#pragma unroll
            for (int t = 0; t < 22; ++t) {
                int q = q0 + t;
                q = (q < 0) ? -q : q;
                q = (q >= LIN) ? (2 * LIN - 2 - q) : q;
                w[t] = in[PHI(ib + q)];
            }
        }

        float lo[4], hi[4];
#pragma unroll
        for (int i = 0; i < 4; ++i) { lo[i] = 0.f; hi[i] = 0.f; }
#pragma unroll
        for (int t = 0; t < 16; ++t) {
            const float cl = FL[t], ch = FH[t];
#pragma unroll
            for (int i = 0; i < 4; ++i) {
                const float v = w[2 * i + t];
                lo[i] = fmaf(v, cl, lo[i]);
                hi[i] = fmaf(v, ch, hi[i]);
            }
        }

        const int ob0 = (2 * p) * LOUT;
        const int ob1 = ob0 + LOUT;
#pragma unroll
        for (int i = 0; i < 4; ++i) {
            if (j0 + i < LOUT) {
                if (LOG) {
                    outg[ob0 + j0 + i] = logf(fmaf(lo[i], lo[i], 1e-12f));
                    outg[ob1 + j0 + i] = logf(fmaf(hi[i], hi[i], 1e-12f));
                } else {
                    outl[PHI(ob0 + j0 + i)] = lo[i];
                    outl[PHI(ob1 + j0 + i)] = hi[i];
                }
            }
        }
    }
}

__global__ __launch_bounds__(256) void dwt_quad(
    const float* __restrict__ x, float* __restrict__ y) {
    __shared__ float bufA[PHI(4152) + 2];  // input 4110, lev5 out 4x1038=4152
    __shared__ float bufB[PHI(4208) + 2];  // lev4 out 2x2062=4124, lev6 out 8x526=4208

    const int m = blockIdx.x;
    const float* row = x + (size_t)m * 4110;
    for (int p = threadIdx.x; p < 4110; p += 256) bufA[PHI(p)] = row[p];
    __syncthreads();

    f47_stage<4110, 1, false>(bufA, bufB, nullptr);  // -> 2x2062
    __syncthreads();
    f47_stage<2062, 2, false>(bufB, bufA, nullptr);  // -> 4x1038
    __syncthreads();
    f47_stage<1038, 4, false>(bufA, bufB, nullptr);  // -> 8x526
    __syncthreads();
    float* out = y + (size_t)m * 16 * 270;
    f47_stage<526, 8, true>(bufB, nullptr, out);     // -> 16x270 + log
}

extern "C" void kernel_launch(void* const* d_in, const int* in_sizes, int n_in,
                              void* d_out, int out_size, void* d_ws, size_t ws_size,
                              hipStream_t stream) {
    const float* in = (const float*)d_in[0];
    float* out = (float*)d_out;
    float* wsA = (float*)d_ws;                 // lev1: 512 x 16395 = 8.39M floats
    float* wsB = (float*)d_ws + 9000000;       // lev3: 2048 x 4110 = 8.42M floats

    // F01: 65536 -> (lev0) 32775 -> (lev1) 16395; 128 rows -> 512 subrows
    { dim3 g(33, 128); dwt_pair<65536, 32775, 16395><<<g, 256, 0, stream>>>(in, wsA); }
    // F23: 16395 -> (lev2) 8205 -> (lev3) 4110; 512 subrows -> 2048 subrows
    { dim3 g(9, 512);  dwt_pair<16395, 8205, 4110><<<g, 256, 0, stream>>>(wsA, wsB); }
    // F47: 4110 -> 2062 -> 1038 -> 526 -> 270(+log); 2048 subrows -> 32768 rows
    dwt_quad<<<2048, 256, 0, stream>>>(wsB, out);
}